// Round 5
// baseline (267.084 us; speedup 1.0000x reference)
//
#include <hip/hip_runtime.h>

// CausalSelfAttention: B=4, T=2048, C=1024, H=16, hd=64
// cast->bf16, QKV GEMM (2-phase dbuf global_load_lds, writes V^T),
// 32x32-MFMA swapped-QK^T flash attention (kt-parity split waves + merge), proj GEMM

#define T_SEQ 2048
#define NB 4
#define NH 16
#define CDIM 1024
#define HD 64
#define BH (NB * NH)
#define QSCALE 0.1803368801111204f  // 0.125 * log2(e)

typedef float f32x4 __attribute__((ext_vector_type(4)));
typedef float f32x16 __attribute__((ext_vector_type(16)));
typedef __bf16 bf16x8 __attribute__((ext_vector_type(8)));
typedef unsigned short u16x8 __attribute__((ext_vector_type(8)));
typedef unsigned short u16x4 __attribute__((ext_vector_type(4)));

__device__ __forceinline__ unsigned short f2b(float f) {
    union { float f; unsigned u; } v; v.f = f;
    unsigned u = v.u;
    u += 0x7FFFu + ((u >> 16) & 1u);   // round-to-nearest-even
    return (unsigned short)(u >> 16);
}

__device__ __forceinline__ f32x4 fzero4() {
    f32x4 z; z[0] = 0.f; z[1] = 0.f; z[2] = 0.f; z[3] = 0.f; return z;
}

__device__ __forceinline__ f32x16 mfma32(bf16x8 a, bf16x8 b, f32x16 c) {
    return __builtin_amdgcn_mfma_f32_32x32x16_bf16(a, b, c, 0, 0, 0);
}

// async global->LDS, 16B/lane; LDS dest = wave-uniform base + lane*16 (HW rule)
__device__ __forceinline__ void gld16(const void* gp, void* lp) {
    __builtin_amdgcn_global_load_lds(
        (const __attribute__((address_space(1))) unsigned int*)gp,
        (__attribute__((address_space(3))) unsigned int*)lp, 16, 0, 0);
}

// ---------------- prep: fp32 -> bf16 cast ----------------
__global__ __launch_bounds__(256) void cast_f32_bf16_kernel(
        const float* __restrict__ in, unsigned short* __restrict__ out, int n8) {
    int i = blockIdx.x * 256 + threadIdx.x;
    int stride = gridDim.x * 256;
    for (; i < n8; i += stride) {
        const float4* p = reinterpret_cast<const float4*>(in) + (size_t)i * 2;
        float4 a = p[0], b = p[1];
        u16x8 o;
        o[0] = f2b(a.x); o[1] = f2b(a.y); o[2] = f2b(a.z); o[3] = f2b(a.w);
        o[4] = f2b(b.x); o[5] = f2b(b.y); o[6] = f2b(b.z); o[7] = f2b(b.w);
        *(reinterpret_cast<u16x8*>(out) + i) = o;
    }
}

// ---------------- prep: transpose + cast [R][C] f32 -> [C][R] bf16 ----------------
__global__ __launch_bounds__(256) void transpose_cast_kernel(
        const float* __restrict__ in, unsigned short* __restrict__ out, int R, int C) {
    __shared__ unsigned short tile[32][33];
    int tx = threadIdx.x, ty = threadIdx.y;
    int c0 = blockIdx.x * 32, r0 = blockIdx.y * 32;
    for (int rr = ty; rr < 32; rr += 8)
        tile[rr][tx] = f2b(in[(size_t)(r0 + rr) * C + c0 + tx]);
    __syncthreads();
    for (int rr = ty; rr < 32; rr += 8)
        out[(size_t)(c0 + rr) * R + r0 + tx] = tile[tx][rr];
}

// ---------------- GEMM: C[M][N] = A[M][K] @ Bt[N][K]^T + bias (2-phase dbuf) ----------------
// EPI=0: fp32 to outF. EPI=1: scatter q(*QSCALE)/k to [BH][T][HD], v to V^T [BH][HD][T].
template <int EPI>
__global__ __launch_bounds__(256) void gemm_bt_kernel(
        const unsigned short* __restrict__ A, const unsigned short* __restrict__ Bt,
        const float* __restrict__ bias, float* __restrict__ outF,
        unsigned short* __restrict__ q_out, unsigned short* __restrict__ k_out,
        unsigned short* __restrict__ v_out, int M, int N, int K) {
    __shared__ alignas(16) unsigned short As[2][128 * 32];
    __shared__ alignas(16) unsigned short Bs[2][128 * 32];

    int tid = threadIdx.x;
    int wid = tid >> 6, lane = tid & 63;
    int g = lane >> 4, lc = lane & 15;
    int wr = (wid >> 1) * 64, wc = (wid & 1) * 64;
    int m0 = blockIdx.y * 128, n0 = blockIdx.x * 128;

    f32x4 acc[4][4];
#pragma unroll
    for (int m = 0; m < 4; ++m)
#pragma unroll
        for (int n = 0; n < 4; ++n) acc[m][n] = fzero4();

    int srow = tid >> 2;
    int scol = (tid & 3) * 8;
    const unsigned short* Ap = A + (size_t)(m0 + srow) * K + scol;
    const unsigned short* Bp = Bt + (size_t)(n0 + srow) * K + scol;
    int ldst = (wid * 16) * 32;
    int ldst2 = (64 + wid * 16) * 32;

#define GSTAGE(BUF, KOFF)                                      \
    gld16(Ap + (KOFF), &As[BUF][ldst]);                        \
    gld16(Ap + (size_t)64 * K + (KOFF), &As[BUF][ldst2]);      \
    gld16(Bp + (KOFF), &Bs[BUF][ldst]);                        \
    gld16(Bp + (size_t)64 * K + (KOFF), &Bs[BUF][ldst2]);

    GSTAGE(0, 0)
    __syncthreads();

    int nk = K >> 5;
    for (int it = 0; it < nk; ++it) {
        int cur = it & 1;
        if (it + 1 < nk) { GSTAGE(cur ^ 1, (it + 1) << 5) }

        bf16x8 af[4], bfr[4];
#pragma unroll
        for (int m = 0; m < 4; ++m)
            af[m] = *(const bf16x8*)&As[cur][(wr + m * 16 + lc) * 32 + g * 8];
#pragma unroll
        for (int n = 0; n < 4; ++n)
            bfr[n] = *(const bf16x8*)&Bs[cur][(wc + n * 16 + lc) * 32 + g * 8];
#pragma unroll
        for (int m = 0; m < 4; ++m)
#pragma unroll
            for (int n = 0; n < 4; ++n)
                acc[m][n] = __builtin_amdgcn_mfma_f32_16x16x32_bf16(af[m], bfr[n], acc[m][n], 0, 0, 0);

        __syncthreads();  // drains my prefetch (vmcnt) + everyone's ds_reads
    }
#undef GSTAGE

#pragma unroll
    for (int m = 0; m < 4; ++m) {
        int rowb = m0 + wr + m * 16 + g * 4;
#pragma unroll
        for (int n = 0; n < 4; ++n) {
            int col = n0 + wc + n * 16 + lc;
            float bv = bias[col];
            if (EPI == 0) {
#pragma unroll
                for (int i = 0; i < 4; ++i)
                    outF[(size_t)(rowb + i) * N + col] = acc[m][n][i] + bv;
            } else {
                int which = col >> 10;
                int c = col & 1023;
                int h = c >> 6, d = c & 63;
                int bh_ = (rowb >> 11) * NH + h;
                int tl = rowb & 2047;
                if (which == 2) {
                    u16x4 vq;
#pragma unroll
                    for (int i = 0; i < 4; ++i) vq[i] = f2b(acc[m][n][i] + bv);
                    *(u16x4*)&v_out[(size_t)bh_ * (HD * T_SEQ) + (size_t)d * T_SEQ + tl] = vq;
                } else {
                    unsigned short* dst = which ? k_out : q_out;
                    float sc = which ? 1.0f : QSCALE;
#pragma unroll
                    for (int i = 0; i < 4; ++i)
                        dst[((size_t)bh_ * T_SEQ + tl + i) * HD + d] =
                            f2b((acc[m][n][i] + bv) * sc);
                }
            }
        }
    }
}

// ---------------- flash attention: 32x32 MFMA, swapped QK^T ----------------
// Grid 512 blocks x 512 thr (8 waves). Block = 4 pairs x 2 kt-parity halves.
// Wave (pi, hf): pair p = 4*b8+pi, computes tiles at kt%2==hf; merge halves at end.
// KV double-buffered in LDS (16KB tile, XOR-swizzled), prefetch next kt during compute.
__global__ __launch_bounds__(512, 4) void attn32_kernel(
        const unsigned short* __restrict__ Qb, const unsigned short* __restrict__ Kb,
        const unsigned short* __restrict__ Vt, unsigned short* __restrict__ Yb) {
    __shared__ alignas(16) char smem[34816];  // 32KB KV dbuf, 34KB merge (aliased)

    int tid = threadIdx.x;
    int wid = tid >> 6, lane = tid & 63;
    int ql = lane & 31, hi = lane >> 5;
    int ql7 = ql & 7;
    int pi = wid & 3, hf = wid >> 2;

    // XCD swizzle: 512 blocks -> each XCD owns 8 whole heads
    int id = blockIdx.x;
    int swz = (id & 7) * 64 + (id >> 3);
    int bh = swz >> 3;
    int b8 = swz & 7;
    int p = b8 * 4 + pi;
    size_t hb = (size_t)bh * (T_SEQ * HD);

    int qA0 = p * 32, qB0 = (63 - p) * 32;
    int ktA = p >> 1;
    int ktB = 31 - (p >> 1);
    int nt = 32 - 2 * b8;

    // persistent Q B-frag for tile B (col=q=ql, elems d = dstep*16 + hi*8 + e)
    bf16x8 qB_[4];
    const unsigned short* QBp = Qb + hb + (size_t)(qB0 + ql) * HD + hi * 8;
#pragma unroll
    for (int d = 0; d < 4; ++d) qB_[d] = *(const bf16x8*)(QBp + d * 16);
    const unsigned short* QAp = Qb + hb + (size_t)(qA0 + ql) * HD + hi * 8;

    f32x16 zz;
#pragma unroll
    for (int r = 0; r < 16; ++r) zz[r] = 0.f;
    f32x16 oA0 = zz, oA1 = zz, oB0 = zz, oB1 = zz;
    float mA = -__builtin_inff(), lA = 0.f;
    float mB = -__builtin_inff(), lB = 0.f;

    // staging: wave w stages K rows [8w,8w+8) and V rows [8w,8w+8) (1KB each)
    int r8 = lane >> 3;
    int sslot8 = ((lane & 7) ^ r8) * 8;  // pre-swizzled source slot
    const unsigned short* Kg = Kb + hb + (size_t)(wid * 8 + r8) * HD + sslot8;
    const unsigned short* Vg = Vt + hb + (size_t)(wid * 8 + r8) * T_SEQ + sslot8;

    // prologue: stage kt=0 into buf 0
    gld16(Kg, smem + wid * 1024);
    gld16(Vg, smem + 8192 + wid * 1024);
    __syncthreads();

#define KF(K0, D) (*(const bf16x8*)&KB_[(((K0)*32 + ql) << 6) + ((((D)*2 + hi) ^ ql7) << 3)])
#define VF(DB, T) (*(const bf16x8*)&VB_[(((DB)*32 + ql) << 6) + ((((T)*2 + hi) ^ ql7) << 3)])

#define TILE(QF, O0, O1, MI, LI, Q0, DIAG)                                           \
    {                                                                                \
        f32x16 s0_, s1_;                                                             \
        __builtin_amdgcn_s_setprio(1);                                               \
        s0_ = mfma32(KF(0, 0), QF[0], zz);                                           \
        s0_ = mfma32(KF(0, 1), QF[1], s0_);                                          \
        s0_ = mfma32(KF(0, 2), QF[2], s0_);                                          \
        s0_ = mfma32(KF(0, 3), QF[3], s0_);                                          \
        s1_ = mfma32(KF(1, 0), QF[0], zz);                                           \
        s1_ = mfma32(KF(1, 1), QF[1], s1_);                                          \
        s1_ = mfma32(KF(1, 2), QF[2], s1_);                                          \
        s1_ = mfma32(KF(1, 3), QF[3], s1_);                                          \
        __builtin_amdgcn_s_setprio(0);                                               \
        if (DIAG) {                                                                  \
            int qg_ = (Q0) + ql;                                                     \
            _Pragma("unroll")                                                        \
            for (int r = 0; r < 16; ++r) {                                           \
                int kof_ = k0 + 8 * (r >> 2) + (r & 3) + 4 * hi;                     \
                if (kof_ > qg_) s0_[r] = -__builtin_inff();                          \
                if (kof_ + 32 > qg_) s1_[r] = -__builtin_inff();                     \
            }                                                                        \
        }                                                                            \
        float t_[8];                                                                 \
        _Pragma("unroll")                                                            \
        for (int r = 0; r < 8; ++r)                                                  \
            t_[r] = fmaxf(fmaxf(s0_[r], s0_[r + 8]), fmaxf(s1_[r], s1_[r + 8]));     \
        _Pragma("unroll")                                                            \
        for (int r = 0; r < 4; ++r) t_[r] = fmaxf(t_[r], t_[r + 4]);                 \
        float pm_ = fmaxf(fmaxf(t_[0], t_[1]), fmaxf(t_[2], t_[3]));                 \
        pm_ = fmaxf(pm_, __shfl_xor(pm_, 32));                                       \
        float mn_ = MI;                                                              \
        if (!__all((int)(pm_ <= MI + 8.f))) {  /* defer-max: skip rescale if small */ \
            mn_ = fmaxf(MI, pm_);                                                    \
            float f_ = __builtin_amdgcn_exp2f(MI - mn_);                             \
            MI = mn_;                                                                \
            LI *= f_;                                                                \
            O0 *= f_;                                                                \
            O1 *= f_;                                                                \
        }                                                                            \
        _Pragma("unroll")                                                            \
        for (int r = 0; r < 16; ++r) {                                               \
            s0_[r] = __builtin_amdgcn_exp2f(s0_[r] - mn_);                           \
            s1_[r] = __builtin_amdgcn_exp2f(s1_[r] - mn_);                           \
        }                                                                            \
        float u_[8];                                                                 \
        _Pragma("unroll")                                                            \
        for (int r = 0; r < 8; ++r)                                                  \
            u_[r] = (s0_[r] + s0_[r + 8]) + (s1_[r] + s1_[r + 8]);                   \
        _Pragma("unroll")                                                            \
        for (int r = 0; r < 4; ++r) u_[r] += u_[r + 4];                              \
        float ps_ = (u_[0] + u_[1]) + (u_[2] + u_[3]);                               \
        ps_ += __shfl_xor(ps_, 32);                                                  \
        LI += ps_;                                                                   \
        _Pragma("unroll")                                                            \
        for (int K0_ = 0; K0_ < 2; ++K0_) {                                          \
            _Pragma("unroll")                                                        \
            for (int h2_ = 0; h2_ < 2; ++h2_) {                                      \
                float e0_ = K0_ ? s1_[8 * h2_ + 0] : s0_[8 * h2_ + 0];               \
                float e1_ = K0_ ? s1_[8 * h2_ + 1] : s0_[8 * h2_ + 1];               \
                float e2_ = K0_ ? s1_[8 * h2_ + 2] : s0_[8 * h2_ + 2];               \
                float e3_ = K0_ ? s1_[8 * h2_ + 3] : s0_[8 * h2_ + 3];               \
                float e4_ = K0_ ? s1_[8 * h2_ + 4] : s0_[8 * h2_ + 4];               \
                float e5_ = K0_ ? s1_[8 * h2_ + 5] : s0_[8 * h2_ + 5];               \
                float e6_ = K0_ ? s1_[8 * h2_ + 6] : s0_[8 * h2_ + 6];               \
                float e7_ = K0_ ? s1_[8 * h2_ + 7] : s0_[8 * h2_ + 7];               \
                unsigned a_, b_, c_, d_;                                             \
                asm("v_cvt_pk_bf16_f32 %0, %1, %2" : "=v"(a_) : "v"(e0_), "v"(e1_)); \
                asm("v_cvt_pk_bf16_f32 %0, %1, %2" : "=v"(b_) : "v"(e2_), "v"(e3_)); \
                asm("v_cvt_pk_bf16_f32 %0, %1, %2" : "=v"(c_) : "v"(e4_), "v"(e5_)); \
                asm("v_cvt_pk_bf16_f32 %0, %1, %2" : "=v"(d_) : "v"(e6_), "v"(e7_)); \
                asm("v_permlane32_swap_b32 %0, %1" : "+v"(a_), "+v"(c_));            \
                asm("v_permlane32_swap_b32 %0, %1" : "+v"(b_), "+v"(d_));            \
                union { unsigned u[4]; bf16x8 v; } pf_;                              \
                pf_.u[0] = a_; pf_.u[1] = b_; pf_.u[2] = c_; pf_.u[3] = d_;          \
                __builtin_amdgcn_s_setprio(1);                                       \
                O0 = mfma32(VF(0, K0_ * 2 + h2_), pf_.v, O0);                        \
                O1 = mfma32(VF(1, K0_ * 2 + h2_), pf_.v, O1);                        \
                __builtin_amdgcn_s_setprio(0);                                       \
            }                                                                        \
        }                                                                            \
    }

    for (int kt = 0; kt < nt; ++kt) {
        int cur = kt & 1;
        int k0 = kt * 64;
        if (kt + 1 < nt) {  // prefetch next tile into other buffer
            int nb = cur ^ 1;
            gld16(Kg + (size_t)(kt + 1) * 64 * HD, smem + nb * 16384 + wid * 1024);
            gld16(Vg + (kt + 1) * 64, smem + nb * 16384 + 8192 + wid * 1024);
        }
        const unsigned short* KB_ = (const unsigned short*)(smem + cur * 16384);
        const unsigned short* VB_ = (const unsigned short*)(smem + cur * 16384 + 8192);
        if ((kt & 1) == hf) {  // parity split across wave halves
            if (kt <= ktB) TILE(qB_, oB0, oB1, mB, lB, qB0, kt == ktB);
            if (kt <= ktA) {
                bf16x8 qA_[4];
#pragma unroll
                for (int d = 0; d < 4; ++d) qA_[d] = *(const bf16x8*)(QAp + d * 16);
                TILE(qA_, oA0, oA1, mA, lA, qA0, kt == ktA);
            }
        }
        __syncthreads();
    }
#undef TILE
#undef KF
#undef VF

    // merge halves via LDS (2 rounds: pairs {0,1} then {2,3}), then write y
    float* mrg = (float*)smem;
    int bb = bh >> 4, h = bh & 15;
    for (int rr = 0; rr < 2; ++rr) {
        __syncthreads();
        if ((pi >> 1) == rr && hf == 1) {
            float* s0 = mrg + (((pi & 1) * 2 + 0) * 64 + lane) * 34;
            float* s1 = mrg + (((pi & 1) * 2 + 1) * 64 + lane) * 34;
#pragma unroll
            for (int x = 0; x < 16; ++x) {
                s0[x] = oA0[x]; s0[16 + x] = oA1[x];
                s1[x] = oB0[x]; s1[16 + x] = oB1[x];
            }
            s0[32] = mA; s0[33] = lA;
            s1[32] = mB; s1[33] = lB;
        }
        __syncthreads();
        if ((pi >> 1) == rr && hf == 0) {
            const float* s0 = mrg + (((pi & 1) * 2 + 0) * 64 + lane) * 34;
            const float* s1 = mrg + (((pi & 1) * 2 + 1) * 64 + lane) * 34;
            // tile A
            {
                float m1 = s0[32], l1 = s0[33];
                float mm = fmaxf(mA, m1);
                float c0 = __builtin_amdgcn_exp2f(mA - mm);
                float c1 = __builtin_amdgcn_exp2f(m1 - mm);
                float iv = 1.f / (lA * c0 + l1 * c1);
#pragma unroll
                for (int dblk = 0; dblk < 2; ++dblk)
#pragma unroll
                    for (int a = 0; a < 4; ++a) {
                        u16x4 wv;
#pragma unroll
                        for (int i = 0; i < 4; ++i) {
                            float v = ((dblk ? oA1[4 * a + i] : oA0[4 * a + i]) * c0 +
                                       s0[dblk * 16 + 4 * a + i] * c1) * iv;
                            wv[i] = f2b(v);
                        }
                        int dq = dblk * 32 + 8 * a + 4 * hi;
                        *(u16x4*)&Yb[((size_t)(bb * T_SEQ + qA0 + ql)) * CDIM + h * HD + dq] = wv;
                    }
            }
            // tile B
            {
                float m1 = s1[32], l1 = s1[33];
                float mm = fmaxf(mB, m1);
                float c0 = __builtin_amdgcn_exp2f(mB - mm);
                float c1 = __builtin_amdgcn_exp2f(m1 - mm);
                float iv = 1.f / (lB * c0 + l1 * c1);
#pragma unroll
                for (int dblk = 0; dblk < 2; ++dblk)
#pragma unroll
                    for (int a = 0; a < 4; ++a) {
                        u16x4 wv;
#pragma unroll
                        for (int i = 0; i < 4; ++i) {
                            float v = ((dblk ? oB1[4 * a + i] : oB0[4 * a + i]) * c0 +
                                       s1[dblk * 16 + 4 * a + i] * c1) * iv;
                            wv[i] = f2b(v);
                        }
                        int dq = dblk * 32 + 8 * a + 4 * hi;
                        *(u16x4*)&Yb[((size_t)(bb * T_SEQ + qB0 + ql)) * CDIM + h * HD + dq] = wv;
                    }
            }
        }
    }
}

// ---------------- launch ----------------
extern "C" void kernel_launch(void* const* d_in, const int* in_sizes, int n_in,
                              void* d_out, int out_size, void* d_ws, size_t ws_size,
                              hipStream_t stream) {
    const float* x      = (const float*)d_in[0];
    const float* w_attn = (const float*)d_in[1];
    const float* b_attn = (const float*)d_in[2];
    const float* w_proj = (const float*)d_in[3];
    const float* b_proj = (const float*)d_in[4];
    float* out = (float*)d_out;

    // workspace layout (bytes):
    //   0         xb  : x bf16 [8192][1024]         16,777,216  (reused as yb)
    //   16777216  wTa : w_attn^T bf16 [3072][1024]   6,291,456
    //   23068672  wTp : w_proj^T bf16 [1024][1024]   2,097,152
    //   25165824  qb  : [64][2048][64] bf16         16,777,216  (pre-scaled by QSCALE)
    //   41943040  kb  : [64][2048][64] bf16         16,777,216
    //   58720256  vTb : [64][64][2048] bf16         16,777,216  (V^T, written by GEMM1)
    char* ws = (char*)d_ws;
    unsigned short* xb  = (unsigned short*)(ws);
    unsigned short* wTa = (unsigned short*)(ws + 16777216);
    unsigned short* wTp = (unsigned short*)(ws + 23068672);
    unsigned short* qb  = (unsigned short*)(ws + 25165824);
    unsigned short* kb  = (unsigned short*)(ws + 41943040);
    unsigned short* vTb = (unsigned short*)(ws + 58720256);
    unsigned short* yb  = xb;  // alias: xb dead after GEMM1

    cast_f32_bf16_kernel<<<2048, 256, 0, stream>>>(x, xb, (NB * T_SEQ * CDIM) / 8);
    transpose_cast_kernel<<<dim3(3072 / 32, 1024 / 32), dim3(32, 8), 0, stream>>>(
        w_attn, wTa, 1024, 3072);
    transpose_cast_kernel<<<dim3(1024 / 32, 1024 / 32), dim3(32, 8), 0, stream>>>(
        w_proj, wTp, 1024, 1024);

    // QKV GEMM: q (scaled), k row-major; v written transposed per head
    gemm_bt_kernel<1><<<dim3(3072 / 128, 8192 / 128), 256, 0, stream>>>(
        xb, wTa, b_attn, nullptr, qb, kb, vTb, 8192, 3072, 1024);

    // flash attention (1D grid for XCD swizzle; 8 waves = 4 pairs x 2 halves)
    attn32_kernel<<<dim3(512), 512, 0, stream>>>(qb, kb, vTb, yb);

    // proj GEMM -> fp32 out
    gemm_bt_kernel<0><<<dim3(1024 / 128, 8192 / 128), 256, 0, stream>>>(
        yb, wTp, b_proj, out, nullptr, nullptr, nullptr, 8192, 1024, 1024);
}

// Round 6
// 174.007 us; speedup vs baseline: 1.5349x; 1.5349x over previous
//
#include <hip/hip_runtime.h>

// CausalSelfAttention: B=4, T=2048, C=1024, H=16, hd=64
// cast->bf16, QKV GEMM (2-phase dbuf global_load_lds, writes V^T),
// 32x32-MFMA swapped-QK^T flash attention (1 q-tile/wave, 1024 balanced blocks), proj GEMM

#define T_SEQ 2048
#define NB 4
#define NH 16
#define CDIM 1024
#define HD 64
#define BH (NB * NH)
#define QSCALE 0.1803368801111204f  // 0.125 * log2(e)

typedef float f32x4 __attribute__((ext_vector_type(4)));
typedef float f32x16 __attribute__((ext_vector_type(16)));
typedef __bf16 bf16x8 __attribute__((ext_vector_type(8)));
typedef unsigned short u16x8 __attribute__((ext_vector_type(8)));
typedef unsigned short u16x4 __attribute__((ext_vector_type(4)));

__device__ __forceinline__ unsigned short f2b(float f) {
    union { float f; unsigned u; } v; v.f = f;
    unsigned u = v.u;
    u += 0x7FFFu + ((u >> 16) & 1u);   // round-to-nearest-even
    return (unsigned short)(u >> 16);
}

__device__ __forceinline__ f32x4 fzero4() {
    f32x4 z; z[0] = 0.f; z[1] = 0.f; z[2] = 0.f; z[3] = 0.f; return z;
}

__device__ __forceinline__ f32x16 mfma32(bf16x8 a, bf16x8 b, f32x16 c) {
    return __builtin_amdgcn_mfma_f32_32x32x16_bf16(a, b, c, 0, 0, 0);
}

// async global->LDS, 16B/lane; LDS dest = wave-uniform base + lane*16 (HW rule)
__device__ __forceinline__ void gld16(const void* gp, void* lp) {
    __builtin_amdgcn_global_load_lds(
        (const __attribute__((address_space(1))) unsigned int*)gp,
        (__attribute__((address_space(3))) unsigned int*)lp, 16, 0, 0);
}

// ---------------- prep: fp32 -> bf16 cast ----------------
__global__ __launch_bounds__(256) void cast_f32_bf16_kernel(
        const float* __restrict__ in, unsigned short* __restrict__ out, int n8) {
    int i = blockIdx.x * 256 + threadIdx.x;
    int stride = gridDim.x * 256;
    for (; i < n8; i += stride) {
        const float4* p = reinterpret_cast<const float4*>(in) + (size_t)i * 2;
        float4 a = p[0], b = p[1];
        u16x8 o;
        o[0] = f2b(a.x); o[1] = f2b(a.y); o[2] = f2b(a.z); o[3] = f2b(a.w);
        o[4] = f2b(b.x); o[5] = f2b(b.y); o[6] = f2b(b.z); o[7] = f2b(b.w);
        *(reinterpret_cast<u16x8*>(out) + i) = o;
    }
}

// ---------------- prep: transpose + cast [R][C] f32 -> [C][R] bf16 ----------------
__global__ __launch_bounds__(256) void transpose_cast_kernel(
        const float* __restrict__ in, unsigned short* __restrict__ out, int R, int C) {
    __shared__ unsigned short tile[32][33];
    int tx = threadIdx.x, ty = threadIdx.y;
    int c0 = blockIdx.x * 32, r0 = blockIdx.y * 32;
    for (int rr = ty; rr < 32; rr += 8)
        tile[rr][tx] = f2b(in[(size_t)(r0 + rr) * C + c0 + tx]);
    __syncthreads();
    for (int rr = ty; rr < 32; rr += 8)
        out[(size_t)(c0 + rr) * R + r0 + tx] = tile[tx][rr];
}

// ---------------- GEMM: C[M][N] = A[M][K] @ Bt[N][K]^T + bias (2-phase dbuf) ----------------
// EPI=0: fp32 to outF. EPI=1: scatter q(*QSCALE)/k to [BH][T][HD], v to V^T [BH][HD][T].
template <int EPI>
__global__ __launch_bounds__(256) void gemm_bt_kernel(
        const unsigned short* __restrict__ A, const unsigned short* __restrict__ Bt,
        const float* __restrict__ bias, float* __restrict__ outF,
        unsigned short* __restrict__ q_out, unsigned short* __restrict__ k_out,
        unsigned short* __restrict__ v_out, int M, int N, int K) {
    __shared__ alignas(16) unsigned short As[2][128 * 32];
    __shared__ alignas(16) unsigned short Bs[2][128 * 32];

    int tid = threadIdx.x;
    int wid = tid >> 6, lane = tid & 63;
    int g = lane >> 4, lc = lane & 15;
    int wr = (wid >> 1) * 64, wc = (wid & 1) * 64;
    int m0 = blockIdx.y * 128, n0 = blockIdx.x * 128;

    f32x4 acc[4][4];
#pragma unroll
    for (int m = 0; m < 4; ++m)
#pragma unroll
        for (int n = 0; n < 4; ++n) acc[m][n] = fzero4();

    int srow = tid >> 2;
    int scol = (tid & 3) * 8;
    const unsigned short* Ap = A + (size_t)(m0 + srow) * K + scol;
    const unsigned short* Bp = Bt + (size_t)(n0 + srow) * K + scol;
    int ldst = (wid * 16) * 32;
    int ldst2 = (64 + wid * 16) * 32;

#define GSTAGE(BUF, KOFF)                                      \
    gld16(Ap + (KOFF), &As[BUF][ldst]);                        \
    gld16(Ap + (size_t)64 * K + (KOFF), &As[BUF][ldst2]);      \
    gld16(Bp + (KOFF), &Bs[BUF][ldst]);                        \
    gld16(Bp + (size_t)64 * K + (KOFF), &Bs[BUF][ldst2]);

    GSTAGE(0, 0)
    __syncthreads();

    int nk = K >> 5;
    for (int it = 0; it < nk; ++it) {
        int cur = it & 1;
        if (it + 1 < nk) { GSTAGE(cur ^ 1, (it + 1) << 5) }

        bf16x8 af[4], bfr[4];
#pragma unroll
        for (int m = 0; m < 4; ++m)
            af[m] = *(const bf16x8*)&As[cur][(wr + m * 16 + lc) * 32 + g * 8];
#pragma unroll
        for (int n = 0; n < 4; ++n)
            bfr[n] = *(const bf16x8*)&Bs[cur][(wc + n * 16 + lc) * 32 + g * 8];
#pragma unroll
        for (int m = 0; m < 4; ++m)
#pragma unroll
            for (int n = 0; n < 4; ++n)
                acc[m][n] = __builtin_amdgcn_mfma_f32_16x16x32_bf16(af[m], bfr[n], acc[m][n], 0, 0, 0);

        __syncthreads();  // drains my prefetch (vmcnt) + everyone's ds_reads
    }
#undef GSTAGE

#pragma unroll
    for (int m = 0; m < 4; ++m) {
        int rowb = m0 + wr + m * 16 + g * 4;
#pragma unroll
        for (int n = 0; n < 4; ++n) {
            int col = n0 + wc + n * 16 + lc;
            float bv = bias[col];
            if (EPI == 0) {
#pragma unroll
                for (int i = 0; i < 4; ++i)
                    outF[(size_t)(rowb + i) * N + col] = acc[m][n][i] + bv;
            } else {
                int which = col >> 10;
                int c = col & 1023;
                int h = c >> 6, d = c & 63;
                int bh_ = (rowb >> 11) * NH + h;
                int tl = rowb & 2047;
                if (which == 2) {
                    u16x4 vq;
#pragma unroll
                    for (int i = 0; i < 4; ++i) vq[i] = f2b(acc[m][n][i] + bv);
                    *(u16x4*)&v_out[(size_t)bh_ * (HD * T_SEQ) + (size_t)d * T_SEQ + tl] = vq;
                } else {
                    unsigned short* dst = which ? k_out : q_out;
                    float sc = which ? 1.0f : QSCALE;
#pragma unroll
                    for (int i = 0; i < 4; ++i)
                        dst[((size_t)bh_ * T_SEQ + tl + i) * HD + d] =
                            f2b((acc[m][n][i] + bv) * sc);
                }
            }
        }
    }
}

// ---------------- flash attention: 32x32 MFMA, swapped QK^T ----------------
// 1024 blocks x 256 thr (4 waves). Block = (head, qg): q-tiles qg*4 + wid (32 rows each).
// Wave ranges differ by <=1 KV tile. Per-CU balance: per-XCD dispatch rounds alternate
// qg <-> 15-qg so each CU's 4 resident blocks sum to constant work.
// S^T = mfma(K,Q): lane owns q = lane&31 -> lane-local softmax + defer-max.
// KV dbuf in LDS (16KB/tile, XOR-swizzled), prefetch next kt, one barrier per kt.
__global__ __launch_bounds__(256, 4) void attn32_kernel(
        const unsigned short* __restrict__ Qb, const unsigned short* __restrict__ Kb,
        const unsigned short* __restrict__ Vt, unsigned short* __restrict__ Yb) {
    __shared__ alignas(16) char smem[32768];  // 2 x (K 8KB + V 8KB)

    int tid = threadIdx.x;
    int wid = tid >> 6, lane = tid & 63;
    int ql = lane & 31, hi = lane >> 5;
    int ql7 = ql & 7;

    // balanced XCD-aware mapping: id -> (bh, qg)
    int id = blockIdx.x;
    int x = id & 7;          // XCD
    int k = id >> 3;         // 0..127 within XCD
    int r = k >> 5;          // dispatch round 0..3
    int c = k & 31;
    int hh = 2 * r + (c >> 4);
    int j = c & 15;
    int qg = (r & 1) ? (15 - j) : j;
    int bh = x * 8 + hh;
    size_t hb = (size_t)bh * (T_SEQ * HD);

    int qt = qg * 4 + wid;            // this wave's 32-row q-tile
    int q0 = qt * 32;
    int ktMax = qt >> 1;              // last (diagonal) KV tile for this wave
    int ntB = 2 * qg + 2;             // block's KV tile count (max over waves)

    // persistent Q B-frag (col=q=ql, elems d = dstep*16 + hi*8 + e)
    bf16x8 qf[4];
    const unsigned short* Qp = Qb + hb + (size_t)(q0 + ql) * HD + hi * 8;
#pragma unroll
    for (int d = 0; d < 4; ++d) qf[d] = *(const bf16x8*)(Qp + d * 16);

    f32x16 zz;
#pragma unroll
    for (int rr = 0; rr < 16; ++rr) zz[rr] = 0.f;
    f32x16 o0 = zz, o1 = zz;
    float mi = -__builtin_inff(), li = 0.f;

    // staging: wave w covers K rows [16w,16w+16) and V rows [16w,16w+16)
    int r8 = lane >> 3;
    int sslot8 = ((lane & 7) ^ r8) * 8;  // pre-swizzled source slot
    const unsigned short* Kg = Kb + hb + (size_t)(wid * 16 + r8) * HD + sslot8;
    const unsigned short* Vg = Vt + hb + (size_t)(wid * 16 + r8) * T_SEQ + sslot8;

    // prologue: stage kt=0 into buf 0
    gld16(Kg, smem + wid * 2048);
    gld16(Kg + 8 * HD, smem + wid * 2048 + 1024);
    gld16(Vg, smem + 8192 + wid * 2048);
    gld16(Vg + 8 * T_SEQ, smem + 8192 + wid * 2048 + 1024);
    __syncthreads();

#define KF(K0, D) (*(const bf16x8*)&KB_[(((K0)*32 + ql) << 6) + ((((D)*2 + hi) ^ ql7) << 3)])
#define VF(DB, T) (*(const bf16x8*)&VB_[(((DB)*32 + ql) << 6) + ((((T)*2 + hi) ^ ql7) << 3)])

    for (int kt = 0; kt < ntB; ++kt) {
        int cur = kt & 1;
        if (kt + 1 < ntB) {  // prefetch next tile into other buffer
            char* nb = smem + (cur ^ 1) * 16384;
            gld16(Kg + (size_t)(kt + 1) * 64 * HD, nb + wid * 2048);
            gld16(Kg + (size_t)((kt + 1) * 64 + 8) * HD, nb + wid * 2048 + 1024);
            gld16(Vg + (kt + 1) * 64, nb + 8192 + wid * 2048);
            gld16(Vg + (kt + 1) * 64 + 8 * T_SEQ, nb + 8192 + wid * 2048 + 1024);
        }
        if (kt <= ktMax) {
            const unsigned short* KB_ = (const unsigned short*)(smem + cur * 16384);
            const unsigned short* VB_ = (const unsigned short*)(smem + cur * 16384 + 8192);
            int k0 = kt * 64;

            f32x16 s0_, s1_;
            __builtin_amdgcn_s_setprio(1);
            s0_ = mfma32(KF(0, 0), qf[0], zz);
            s0_ = mfma32(KF(0, 1), qf[1], s0_);
            s0_ = mfma32(KF(0, 2), qf[2], s0_);
            s0_ = mfma32(KF(0, 3), qf[3], s0_);
            s1_ = mfma32(KF(1, 0), qf[0], zz);
            s1_ = mfma32(KF(1, 1), qf[1], s1_);
            s1_ = mfma32(KF(1, 2), qf[2], s1_);
            s1_ = mfma32(KF(1, 3), qf[3], s1_);
            __builtin_amdgcn_s_setprio(0);

            if (kt == ktMax) {  // causal mask, diagonal tile only
                int qg_ = q0 + ql;
#pragma unroll
                for (int rr = 0; rr < 16; ++rr) {
                    int kof_ = k0 + 8 * (rr >> 2) + (rr & 3) + 4 * hi;
                    if (kof_ > qg_) s0_[rr] = -__builtin_inff();
                    if (kof_ + 32 > qg_) s1_[rr] = -__builtin_inff();
                }
            }

            // lane-local row max (in exp2 domain; q pre-scaled by 0.125*log2e)
            float t_[8];
#pragma unroll
            for (int rr = 0; rr < 8; ++rr)
                t_[rr] = fmaxf(fmaxf(s0_[rr], s0_[rr + 8]), fmaxf(s1_[rr], s1_[rr + 8]));
#pragma unroll
            for (int rr = 0; rr < 4; ++rr) t_[rr] = fmaxf(t_[rr], t_[rr + 4]);
            float pm_ = fmaxf(fmaxf(t_[0], t_[1]), fmaxf(t_[2], t_[3]));
            pm_ = fmaxf(pm_, __shfl_xor(pm_, 32));

            float mn_ = mi;
            if (!__all((int)(pm_ <= mi + 8.f))) {  // defer-max: skip rescale if small
                mn_ = fmaxf(mi, pm_);
                float f_ = __builtin_amdgcn_exp2f(mi - mn_);
                mi = mn_;
                li *= f_;
                o0 *= f_;
                o1 *= f_;
            }
#pragma unroll
            for (int rr = 0; rr < 16; ++rr) {
                s0_[rr] = __builtin_amdgcn_exp2f(s0_[rr] - mn_);
                s1_[rr] = __builtin_amdgcn_exp2f(s1_[rr] - mn_);
            }
            float u_[8];
#pragma unroll
            for (int rr = 0; rr < 8; ++rr)
                u_[rr] = (s0_[rr] + s0_[rr + 8]) + (s1_[rr] + s1_[rr + 8]);
#pragma unroll
            for (int rr = 0; rr < 4; ++rr) u_[rr] += u_[rr + 4];
            float ps_ = (u_[0] + u_[1]) + (u_[2] + u_[3]);
            ps_ += __shfl_xor(ps_, 32);
            li += ps_;

            // P -> PV B-frag via cvt_pk + permlane32_swap, then O += V^T P^T
#pragma unroll
            for (int K0_ = 0; K0_ < 2; ++K0_) {
#pragma unroll
                for (int h2_ = 0; h2_ < 2; ++h2_) {
                    float e0_ = K0_ ? s1_[8 * h2_ + 0] : s0_[8 * h2_ + 0];
                    float e1_ = K0_ ? s1_[8 * h2_ + 1] : s0_[8 * h2_ + 1];
                    float e2_ = K0_ ? s1_[8 * h2_ + 2] : s0_[8 * h2_ + 2];
                    float e3_ = K0_ ? s1_[8 * h2_ + 3] : s0_[8 * h2_ + 3];
                    float e4_ = K0_ ? s1_[8 * h2_ + 4] : s0_[8 * h2_ + 4];
                    float e5_ = K0_ ? s1_[8 * h2_ + 5] : s0_[8 * h2_ + 5];
                    float e6_ = K0_ ? s1_[8 * h2_ + 6] : s0_[8 * h2_ + 6];
                    float e7_ = K0_ ? s1_[8 * h2_ + 7] : s0_[8 * h2_ + 7];
                    unsigned a_, b_, c_, d_;
                    asm("v_cvt_pk_bf16_f32 %0, %1, %2" : "=v"(a_) : "v"(e0_), "v"(e1_));
                    asm("v_cvt_pk_bf16_f32 %0, %1, %2" : "=v"(b_) : "v"(e2_), "v"(e3_));
                    asm("v_cvt_pk_bf16_f32 %0, %1, %2" : "=v"(c_) : "v"(e4_), "v"(e5_));
                    asm("v_cvt_pk_bf16_f32 %0, %1, %2" : "=v"(d_) : "v"(e6_), "v"(e7_));
                    asm("v_permlane32_swap_b32 %0, %1" : "+v"(a_), "+v"(c_));
                    asm("v_permlane32_swap_b32 %0, %1" : "+v"(b_), "+v"(d_));
                    union { unsigned u[4]; bf16x8 v; } pf_;
                    pf_.u[0] = a_; pf_.u[1] = b_; pf_.u[2] = c_; pf_.u[3] = d_;
                    __builtin_amdgcn_s_setprio(1);
                    o0 = mfma32(VF(0, K0_ * 2 + h2_), pf_.v, o0);
                    o1 = mfma32(VF(1, K0_ * 2 + h2_), pf_.v, o1);
                    __builtin_amdgcn_s_setprio(0);
                }
            }
        }
        __syncthreads();
    }
#undef KF
#undef VF

    // epilogue: O^T[d][q]: q = q0+ql, d = dblk*32 + 8a + i + 4hi
    int bb = bh >> 4, h = bh & 15;
    float iv = 1.0f / li;
#pragma unroll
    for (int dblk = 0; dblk < 2; ++dblk) {
#pragma unroll
        for (int a = 0; a < 4; ++a) {
            u16x4 wv;
#pragma unroll
            for (int i = 0; i < 4; ++i)
                wv[i] = f2b((dblk ? o1[4 * a + i] : o0[4 * a + i]) * iv);
            int dq = dblk * 32 + 8 * a + 4 * hi;
            *(u16x4*)&Yb[((size_t)(bb * T_SEQ + q0 + ql)) * CDIM + h * HD + dq] = wv;
        }
    }
}

// ---------------- launch ----------------
extern "C" void kernel_launch(void* const* d_in, const int* in_sizes, int n_in,
                              void* d_out, int out_size, void* d_ws, size_t ws_size,
                              hipStream_t stream) {
    const float* x      = (const float*)d_in[0];
    const float* w_attn = (const float*)d_in[1];
    const float* b_attn = (const float*)d_in[2];
    const float* w_proj = (const float*)d_in[3];
    const float* b_proj = (const float*)d_in[4];
    float* out = (float*)d_out;

    // workspace layout (bytes):
    //   0         xb  : x bf16 [8192][1024]         16,777,216  (reused as yb)
    //   16777216  wTa : w_attn^T bf16 [3072][1024]   6,291,456
    //   23068672  wTp : w_proj^T bf16 [1024][1024]   2,097,152
    //   25165824  qb  : [64][2048][64] bf16         16,777,216  (pre-scaled by QSCALE)
    //   41943040  kb  : [64][2048][64] bf16         16,777,216
    //   58720256  vTb : [64][64][2048] bf16         16,777,216  (V^T, written by GEMM1)
    char* ws = (char*)d_ws;
    unsigned short* xb  = (unsigned short*)(ws);
    unsigned short* wTa = (unsigned short*)(ws + 16777216);
    unsigned short* wTp = (unsigned short*)(ws + 23068672);
    unsigned short* qb  = (unsigned short*)(ws + 25165824);
    unsigned short* kb  = (unsigned short*)(ws + 41943040);
    unsigned short* vTb = (unsigned short*)(ws + 58720256);
    unsigned short* yb  = xb;  // alias: xb dead after GEMM1

    cast_f32_bf16_kernel<<<2048, 256, 0, stream>>>(x, xb, (NB * T_SEQ * CDIM) / 8);
    transpose_cast_kernel<<<dim3(3072 / 32, 1024 / 32), dim3(32, 8), 0, stream>>>(
        w_attn, wTa, 1024, 3072);
    transpose_cast_kernel<<<dim3(1024 / 32, 1024 / 32), dim3(32, 8), 0, stream>>>(
        w_proj, wTp, 1024, 1024);

    // QKV GEMM: q (scaled), k row-major; v written transposed per head
    gemm_bt_kernel<1><<<dim3(3072 / 128, 8192 / 128), 256, 0, stream>>>(
        xb, wTa, b_attn, nullptr, qb, kb, vTb, 8192, 3072, 1024);

    // flash attention: 1024 balanced blocks x 4 waves
    attn32_kernel<<<dim3(1024), 256, 0, stream>>>(qb, kb, vTb, yb);

    // proj GEMM -> fp32 out
    gemm_bt_kernel<0><<<dim3(1024 / 128, 8192 / 128), 256, 0, stream>>>(
        yb, wTp, b_proj, out, nullptr, nullptr, nullptr, 8192, 1024, 1024);
}